// Round 1
// baseline (22008.833 us; speedup 1.0000x reference)
//
#include <hip/hip_runtime.h>
#include <stdint.h>

#define HID 1024
#define G4  4096
#define BB  64

typedef short short8v __attribute__((ext_vector_type(8)));
typedef float float4v __attribute__((ext_vector_type(4)));
typedef unsigned long long ull;

static __device__ __forceinline__ unsigned short f2bf(float f) {
    unsigned u = __builtin_bit_cast(unsigned, f);
    u += 0x7fffu + ((u >> 16) & 1u);
    return (unsigned short)(u >> 16);
}
static __device__ __forceinline__ float bf2f(unsigned short s) {
    unsigned u = ((unsigned)s) << 16;
    return __builtin_bit_cast(float, u);
}
static __device__ __forceinline__ float sigm(float x) { return 1.0f / (1.0f + __expf(-x)); }
static __device__ __forceinline__ float tanh_fast(float x) { return 2.0f / (1.0f + __expf(-2.0f * x)) - 1.0f; }

// ---------------- prep: bf16 converts + unit-major reorder + offsets ----------------
__global__ void prep_kernel(const float* __restrict__ data,
                            const int* __restrict__ bs_raw,
                            const float* __restrict__ Wih, const float* __restrict__ Whh,
                            const float* __restrict__ bih, const float* __restrict__ bhh,
                            const float* __restrict__ h0,
                            unsigned short* __restrict__ xb,
                            unsigned short* __restrict__ wih_r,
                            unsigned short* __restrict__ whh_r,
                            float* __restrict__ bias_r,
                            unsigned short* __restrict__ hb0, unsigned short* __restrict__ hb1,
                            int* __restrict__ bs_n, int* __restrict__ offs,
                            unsigned* __restrict__ bar,
                            int total, int T)
{
    int bid = blockIdx.x, tid = threadIdx.x;
    if (bid == 0) {
        __shared__ int sbs[1024];
        bool is64 = (T > 1) && (bs_raw[1] == 0);   // int64 batch_sizes => low word at 2*t
        for (int t = tid; t < T && t < 1024; t += 256) sbs[t] = is64 ? bs_raw[2 * t] : bs_raw[t];
        __syncthreads();
        if (tid == 0) {
            int acc = 0;
            for (int t = 0; t < T; ++t) { bs_n[t] = sbs[t]; offs[t] = acc; acc += sbs[t]; }
            bar[0] = 0u;
        }
        return;
    }
    long N0 = (long)total * (HID / 4);
    long N1 = N0 + (long)G4 * (HID / 4);
    long N2 = N1 + (long)G4 * (HID / 4);
    long N3 = N2 + G4;
    long N4 = N3 + BB * (HID / 4);
    long stride = (long)(gridDim.x - 1) * 256;
    for (long i = (long)(bid - 1) * 256 + tid; i < N4; i += stride) {
        if (i < N0) {
            float4 d = ((const float4*)data)[i];
            ((ushort4*)xb)[i] = make_ushort4(f2bf(d.x), f2bf(d.y), f2bf(d.z), f2bf(d.w));
        } else if (i < N1) {
            long j = i - N0; int r = (int)(j >> 8); int k4 = (int)(j & 255);
            int u = r >> 2, g = r & 3;
            float4 d = ((const float4*)Wih)[(long)(g * HID + u) * (HID / 4) + k4];
            ((ushort4*)wih_r)[j] = make_ushort4(f2bf(d.x), f2bf(d.y), f2bf(d.z), f2bf(d.w));
        } else if (i < N2) {
            long j = i - N1; int r = (int)(j >> 8); int k4 = (int)(j & 255);
            int u = r >> 2, g = r & 3;
            float4 d = ((const float4*)Whh)[(long)(g * HID + u) * (HID / 4) + k4];
            ((ushort4*)whh_r)[j] = make_ushort4(f2bf(d.x), f2bf(d.y), f2bf(d.z), f2bf(d.w));
        } else if (i < N3) {
            int r = (int)(i - N2); int u = r >> 2, g = r & 3;
            bias_r[r] = bih[g * HID + u] + bhh[g * HID + u];
        } else {
            long j = i - N3;
            float4 d = ((const float4*)h0)[j];
            ushort4 o = make_ushort4(f2bf(d.x), f2bf(d.y), f2bf(d.z), f2bf(d.w));
            ((ushort4*)hb0)[j] = o;
            ((ushort4*)hb1)[j] = o;
        }
    }
}

// ---------------- input GEMM: gI = xb @ wih_r^T  (bf16 out) ----------------
__global__ __launch_bounds__(256) void gemm_kernel(const unsigned short* __restrict__ xb,
                                                   const unsigned short* __restrict__ wr,
                                                   unsigned short* __restrict__ gI)
{
    __shared__ unsigned short As[128 * 32];
    __shared__ unsigned short Bs[128 * 32];
    int tid = threadIdx.x;
    int l = tid & 63;
    int w = tid >> 6;
    int m = l & 15, q = l >> 4;
    int mtile = blockIdx.x, ntile = blockIdx.y;

    const unsigned short* pa = xb + (long)(mtile * 128 + (tid >> 2)) * HID + (tid & 3) * 8;
    const unsigned short* pb = wr + (long)(ntile * 128 + (tid >> 2)) * HID + (tid & 3) * 8;
    unsigned short* la = As + (tid >> 2) * 32 + (tid & 3) * 8;
    unsigned short* lb = Bs + (tid >> 2) * 32 + (tid & 3) * 8;

    int RM = (w >> 1) * 64, CN = (w & 1) * 64;
    float4v acc[4][4];
#pragma unroll
    for (int i = 0; i < 4; ++i)
#pragma unroll
        for (int j = 0; j < 4; ++j) acc[i][j] = (float4v){0.f, 0.f, 0.f, 0.f};

    for (int kt = 0; kt < HID; kt += 32) {
        short8v a0 = *(const short8v*)(pa + kt);
        short8v a1 = *(const short8v*)(pa + 64 * HID + kt);
        short8v b0 = *(const short8v*)(pb + kt);
        short8v b1 = *(const short8v*)(pb + 64 * HID + kt);
        __syncthreads();
        *(short8v*)la = a0;
        *(short8v*)(la + 64 * 32) = a1;
        *(short8v*)lb = b0;
        *(short8v*)(lb + 64 * 32) = b1;
        __syncthreads();
        short8v av[4], bv[4];
#pragma unroll
        for (int i = 0; i < 4; ++i) av[i] = *(const short8v*)&As[(RM + i * 16 + m) * 32 + q * 8];
#pragma unroll
        for (int j = 0; j < 4; ++j) bv[j] = *(const short8v*)&Bs[(CN + j * 16 + m) * 32 + q * 8];
#pragma unroll
        for (int i = 0; i < 4; ++i)
#pragma unroll
            for (int j = 0; j < 4; ++j)
                acc[i][j] = __builtin_amdgcn_mfma_f32_16x16x32_bf16(av[i], bv[j], acc[i][j], 0, 0, 0);
    }
#pragma unroll
    for (int i = 0; i < 4; ++i)
#pragma unroll
        for (int j = 0; j < 4; ++j)
#pragma unroll
            for (int r = 0; r < 4; ++r) {
                int grow = mtile * 128 + RM + i * 16 + q * 4 + r;
                int gcol = ntile * 128 + CN + j * 16 + m;
                gI[(long)grow * G4 + gcol] = f2bf(acc[i][j][r]);
            }
}

// ---------------- persistent recurrent kernel ----------------
// 64 blocks x 1024 threads. Block bid owns hidden units [bid*16, +16)
// = gate cols [bid*64, +64). 16 waves = 4 row-groups (rg) x 4 K-slices (kq).
// K-split: each wave loads its h A-fragment (rows 16rg..+16, K kq*256..+256)
// DIRECTLY from the agent-coherent h buffer (no LDS staging, h read exactly
// once per block). Each wave accumulates all 4 cg-tiles for its K-slice and
// writes partials to a per-kq sg region; activation threads sum 4 partials.
// Barrier: per-wave release (each wave polls the counter; no fan-out sync).
__global__ __launch_bounds__(1024) void lstm_kernel(
    const unsigned short* __restrict__ gI,
    const unsigned short* __restrict__ whh_r,
    const float* __restrict__ bias_r,
    unsigned short* __restrict__ hb0, unsigned short* __restrict__ hb1,
    const float* __restrict__ h0, const float* __restrict__ c0,
    const int* __restrict__ bs_n, const int* __restrict__ offs,
    unsigned* __restrict__ bar,
    float* __restrict__ out, float* __restrict__ hf, float* __restrict__ cf,
    int T)
{
    // 4 partial-gate regions, row pitch 68 floats (272B: lanes u0..7 hit 8
    // distinct 16B slots -> conflict-free b128 reads; writes are 2-way = free)
    __shared__ __align__(16) float sg[4 * 64 * 68];   // 69.6 KB
    __shared__ int sbs[1024], soff[1024];

    int tid = threadIdx.x, bid = blockIdx.x;
    int lane = tid & 63;
    int w = tid >> 6;            // wave 0..15
    int m = lane & 15, q = lane >> 4;
    int rg = w & 3, kq = w >> 2; // row-group, K-slice

    for (int i = tid; i < T && i < 1024; i += 1024) { sbs[i] = bs_n[i]; soff[i] = offs[i]; }

    // activation-phase thread mapping
    int u = tid & 15;            // unit within block
    int row = tid >> 4;          // batch row 0..63
    int col = bid * 16 + u;      // global hidden unit
    float c_reg = c0[row * HID + col];
    float h_reg = h0[row * HID + col];
    float4 bia = *(const float4*)&bias_r[bid * 64 + 4 * u];

    // W_hh fragment bases, one per cg (L1/L2-resident 131KB slice per block)
    const unsigned short* wp0 = whh_r + (size_t)(bid * 64 + m) * HID + kq * 256 + q * 8;
    const unsigned short* wp1 = wp0 + 16 * HID;
    const unsigned short* wp2 = wp0 + 32 * HID;
    const unsigned short* wp3 = wp0 + 48 * HID;

    // A-fragment offset within h buffer (ull units): row stride 256, kq 64, q 2
    int aoff = (rg * 16 + m) * 256 + kq * 64 + q * 2;

    // sg addresses
    float* sgw = sg + kq * 4352 + (rg * 16 + q * 4) * 68 + m;
    const float* sgr = sg + row * 68 + 4 * u;

    __syncthreads();

    // gI prefetch for t=0 (double-prefetch pipeline: gv = step t, gvn = t+1)
    ushort4 gv = make_ushort4(0, 0, 0, 0);
    {
        int bs0 = sbs[0];
        if (row < bs0)
            gv = *(const ushort4*)(gI + (size_t)(soff[0] + row) * G4 + bid * 64 + 4 * u);
    }

    for (int t = 0; t < T; ++t) {
        const ull* hq = (const ull*)((t & 1) ? hb1 : hb0) + aoff;
        unsigned* hn = (unsigned*)((t & 1) ? hb0 : hb1);
        int bs = sbs[t], off = soff[t];
        int bsn = (t + 1 < T) ? sbs[t + 1] : 0;
        int offn = (t + 1 < T) ? soff[t + 1] : 0;

        // A-fragment loads: agent-scope 8B pairs (IC-coherent), all in flight
        ull ar[16];
#pragma unroll
        for (int k = 0; k < 8; ++k) {
            ar[2 * k]     = __hip_atomic_load(hq + k * 8,     __ATOMIC_RELAXED, __HIP_MEMORY_SCOPE_AGENT);
            ar[2 * k + 1] = __hip_atomic_load(hq + k * 8 + 1, __ATOMIC_RELAXED, __HIP_MEMORY_SCOPE_AGENT);
        }

        // gI prefetch for t+1 — issued a full step early; HBM latency hides
        // under the MFMA phase instead of under the publish drain
        ushort4 gvn = make_ushort4(0, 0, 0, 0);
        if (row < bsn)
            gvn = *(const ushort4*)(gI + (size_t)(offn + row) * G4 + bid * 64 + 4 * u);

        // partial gates over this wave's K-slice: 4 independent acc chains
        float4v a0 = (float4v){0.f, 0.f, 0.f, 0.f}, a1 = a0, a2 = a0, a3 = a0;
#pragma unroll
        for (int k = 0; k < 8; ++k) {
            union { ull u2[2]; short8v s8; } av;
            av.u2[0] = ar[2 * k]; av.u2[1] = ar[2 * k + 1];
            short8v b0 = *(const short8v*)(wp0 + k * 32);
            short8v b1 = *(const short8v*)(wp1 + k * 32);
            short8v b2 = *(const short8v*)(wp2 + k * 32);
            short8v b3 = *(const short8v*)(wp3 + k * 32);
            a0 = __builtin_amdgcn_mfma_f32_16x16x32_bf16(av.s8, b0, a0, 0, 0, 0);
            a1 = __builtin_amdgcn_mfma_f32_16x16x32_bf16(av.s8, b1, a1, 0, 0, 0);
            a2 = __builtin_amdgcn_mfma_f32_16x16x32_bf16(av.s8, b2, a2, 0, 0, 0);
            a3 = __builtin_amdgcn_mfma_f32_16x16x32_bf16(av.s8, b3, a3, 0, 0, 0);
        }
#pragma unroll
        for (int r = 0; r < 4; ++r) {
            sgw[r * 68 +  0] = a0[r];
            sgw[r * 68 + 16] = a1[r];
            sgw[r * 68 + 32] = a2[r];
            sgw[r * 68 + 48] = a3[r];
        }
        __syncthreads();   // [B] all partials in sg

        // activation: thread = (row, unit); sum 4 K-partials
        float4 g0 = *(const float4*)(sgr);
        float4 g1 = *(const float4*)(sgr + 4352);
        float4 g2 = *(const float4*)(sgr + 8704);
        float4 g3 = *(const float4*)(sgr + 13056);
        if (row < bs) {
            float gi = g0.x + g1.x + g2.x + g3.x + bia.x + bf2f(gv.x);
            float gf = g0.y + g1.y + g2.y + g3.y + bia.y + bf2f(gv.y);
            float gg = g0.z + g1.z + g2.z + g3.z + bia.z + bf2f(gv.z);
            float go = g0.w + g1.w + g2.w + g3.w + bia.w + bf2f(gv.w);
            float fi = sigm(gi), ff = sigm(gf), fg = tanh_fast(gg), fo = sigm(go);
            c_reg = ff * c_reg + fi * fg;
            float hv = fo * tanh_fast(c_reg);
            h_reg = hv;
            out[(size_t)(off + row) * HID + col] = hv;
            if (t + 1 >= T || row >= bsn) {
                hf[row * HID + col] = hv;
                cf[row * HID + col] = c_reg;
            }
        }
        gv = gvn;

        // publish h: pack 2 cols -> uint, agent-scope store (write-through IC)
        {
            float hp = __shfl_xor(h_reg, 1);
            if ((u & 1) == 0) {
                unsigned pk = (unsigned)f2bf(h_reg) | ((unsigned)f2bf(hp) << 16);
                __hip_atomic_store(hn + row * (HID / 2) + bid * 8 + (u >> 1), pk,
                                   __ATOMIC_RELAXED, __HIP_MEMORY_SCOPE_AGENT);
            }
        }

        if (t + 1 < T) {
            asm volatile("s_waitcnt vmcnt(0)" ::: "memory");   // publishes drained
            __syncthreads();   // [C] whole block's h visible; also fences sg reads
            if (tid == 0)
                __hip_atomic_fetch_add(bar, 1u, __ATOMIC_RELAXED, __HIP_MEMORY_SCOPE_AGENT);
            unsigned tgt = (unsigned)(t + 1) * 64u;
            // per-wave release: each wave's lane 0 polls; no block-wide fan-out sync
            if (lane == 0) {
                while (__hip_atomic_load(bar, __ATOMIC_RELAXED, __HIP_MEMORY_SCOPE_AGENT) < tgt)
                    __builtin_amdgcn_s_sleep(1);
            }
            asm volatile("" ::: "memory");   // keep next-step loads below the poll
        }
    }
}

extern "C" void kernel_launch(void* const* d_in, const int* in_sizes, int n_in,
                              void* d_out, int out_size, void* d_ws, size_t ws_size,
                              hipStream_t stream)
{
    const float* data = (const float*)d_in[0];
    const int* bs_raw = (const int*)d_in[1];
    const float* Wih = (const float*)d_in[2];
    const float* Whh = (const float*)d_in[3];
    const float* bih = (const float*)d_in[4];
    const float* bhh = (const float*)d_in[5];
    const float* h0 = (const float*)d_in[6];
    const float* c0 = (const float*)d_in[7];
    int total = in_sizes[0] / HID;     // 47872
    int T = in_sizes[1];               // 1000

    char* p = (char*)d_ws;
    unsigned short* gI = (unsigned short*)p;     p += (size_t)total * G4 * 2;
    unsigned short* xb = (unsigned short*)p;     p += (size_t)total * HID * 2;
    unsigned short* wih_r = (unsigned short*)p;  p += (size_t)G4 * HID * 2;
    unsigned short* whh_r = (unsigned short*)p;  p += (size_t)G4 * HID * 2;
    float* bias_r = (float*)p;                   p += (size_t)G4 * 4;
    unsigned short* hbuf0 = (unsigned short*)p;  p += (size_t)BB * HID * 2;
    unsigned short* hbuf1 = (unsigned short*)p;  p += (size_t)BB * HID * 2;
    int* bs_n = (int*)p;                         p += 4096;
    int* offs = (int*)p;                         p += 4096;
    unsigned* bar = (unsigned*)p;                p += 256;

    float* out = (float*)d_out;
    float* hf = out + (size_t)total * HID;
    float* cf = hf + (size_t)BB * HID;

    prep_kernel<<<4097, 256, 0, stream>>>(data, bs_raw, Wih, Whh, bih, bhh, h0,
                                          xb, wih_r, whh_r, bias_r, hbuf0, hbuf1,
                                          bs_n, offs, bar, total, T);
    gemm_kernel<<<dim3(total / 128, G4 / 128), 256, 0, stream>>>(xb, wih_r, gI);
    lstm_kernel<<<64, 1024, 0, stream>>>(gI, whh_r, bias_r, hbuf0, hbuf1, h0, c0,
                                         bs_n, offs, bar, out, hf, cf, T);
}

// Round 3
// 15222.324 us; speedup vs baseline: 1.4458x; 1.4458x over previous
//
#include <hip/hip_runtime.h>
#include <stdint.h>

#define HID 1024
#define G4  4096
#define BB  64

typedef short short8v __attribute__((ext_vector_type(8)));
typedef float float4v __attribute__((ext_vector_type(4)));
typedef unsigned long long ull;

static __device__ __forceinline__ unsigned short f2bf(float f) {
    unsigned u = __builtin_bit_cast(unsigned, f);
    u += 0x7fffu + ((u >> 16) & 1u);
    return (unsigned short)(u >> 16);
}
static __device__ __forceinline__ float bf2f(unsigned short s) {
    unsigned u = ((unsigned)s) << 16;
    return __builtin_bit_cast(float, u);
}
static __device__ __forceinline__ float sigm(float x) { return 1.0f / (1.0f + __expf(-x)); }
static __device__ __forceinline__ float tanh_fast(float x) { return 2.0f / (1.0f + __expf(-2.0f * x)) - 1.0f; }

// ---------------- prep: bf16 converts + unit-major reorder + offsets ----------------
__global__ void prep_kernel(const float* __restrict__ data,
                            const int* __restrict__ bs_raw,
                            const float* __restrict__ Wih, const float* __restrict__ Whh,
                            const float* __restrict__ bih, const float* __restrict__ bhh,
                            const float* __restrict__ h0,
                            unsigned short* __restrict__ xb,
                            unsigned short* __restrict__ wih_r,
                            unsigned short* __restrict__ whh_r,
                            float* __restrict__ bias_r,
                            unsigned short* __restrict__ hb0, unsigned short* __restrict__ hb1,
                            int* __restrict__ bs_n, int* __restrict__ offs,
                            unsigned* __restrict__ bar,
                            int total, int T)
{
    int bid = blockIdx.x, tid = threadIdx.x;
    if (bid == 0) {
        __shared__ int sbs[1024];
        bool is64 = (T > 1) && (bs_raw[1] == 0);   // int64 batch_sizes => low word at 2*t
        for (int t = tid; t < T && t < 1024; t += 256) sbs[t] = is64 ? bs_raw[2 * t] : bs_raw[t];
        __syncthreads();
        if (tid == 0) {
            int acc = 0;
            for (int t = 0; t < T; ++t) { bs_n[t] = sbs[t]; offs[t] = acc; acc += sbs[t]; }
            bar[0] = 0u;
        }
        return;
    }
    long N0 = (long)total * (HID / 4);
    long N1 = N0 + (long)G4 * (HID / 4);
    long N2 = N1 + (long)G4 * (HID / 4);
    long N3 = N2 + G4;
    long N4 = N3 + BB * (HID / 4);
    long stride = (long)(gridDim.x - 1) * 256;
    for (long i = (long)(bid - 1) * 256 + tid; i < N4; i += stride) {
        if (i < N0) {
            float4 d = ((const float4*)data)[i];
            ((ushort4*)xb)[i] = make_ushort4(f2bf(d.x), f2bf(d.y), f2bf(d.z), f2bf(d.w));
        } else if (i < N1) {
            long j = i - N0; int r = (int)(j >> 8); int k4 = (int)(j & 255);
            int u = r >> 2, g = r & 3;
            float4 d = ((const float4*)Wih)[(long)(g * HID + u) * (HID / 4) + k4];
            ((ushort4*)wih_r)[j] = make_ushort4(f2bf(d.x), f2bf(d.y), f2bf(d.z), f2bf(d.w));
        } else if (i < N2) {
            long j = i - N1; int r = (int)(j >> 8); int k4 = (int)(j & 255);
            int u = r >> 2, g = r & 3;
            float4 d = ((const float4*)Whh)[(long)(g * HID + u) * (HID / 4) + k4];
            ((ushort4*)whh_r)[j] = make_ushort4(f2bf(d.x), f2bf(d.y), f2bf(d.z), f2bf(d.w));
        } else if (i < N3) {
            int r = (int)(i - N2); int u = r >> 2, g = r & 3;
            bias_r[r] = bih[g * HID + u] + bhh[g * HID + u];
        } else {
            long j = i - N3;
            float4 d = ((const float4*)h0)[j];
            ushort4 o = make_ushort4(f2bf(d.x), f2bf(d.y), f2bf(d.z), f2bf(d.w));
            ((ushort4*)hb0)[j] = o;
            ((ushort4*)hb1)[j] = o;
        }
    }
}

// ---------------- input GEMM: gI = xb @ wih_r^T  (bf16 out) ----------------
__global__ __launch_bounds__(256) void gemm_kernel(const unsigned short* __restrict__ xb,
                                                   const unsigned short* __restrict__ wr,
                                                   unsigned short* __restrict__ gI)
{
    __shared__ unsigned short As[128 * 32];
    __shared__ unsigned short Bs[128 * 32];
    int tid = threadIdx.x;
    int l = tid & 63;
    int w = tid >> 6;
    int m = l & 15, q = l >> 4;
    int mtile = blockIdx.x, ntile = blockIdx.y;

    const unsigned short* pa = xb + (long)(mtile * 128 + (tid >> 2)) * HID + (tid & 3) * 8;
    const unsigned short* pb = wr + (long)(ntile * 128 + (tid >> 2)) * HID + (tid & 3) * 8;
    unsigned short* la = As + (tid >> 2) * 32 + (tid & 3) * 8;
    unsigned short* lb = Bs + (tid >> 2) * 32 + (tid & 3) * 8;

    int RM = (w >> 1) * 64, CN = (w & 1) * 64;
    float4v acc[4][4];
#pragma unroll
    for (int i = 0; i < 4; ++i)
#pragma unroll
        for (int j = 0; j < 4; ++j) acc[i][j] = (float4v){0.f, 0.f, 0.f, 0.f};

    for (int kt = 0; kt < HID; kt += 32) {
        short8v a0 = *(const short8v*)(pa + kt);
        short8v a1 = *(const short8v*)(pa + 64 * HID + kt);
        short8v b0 = *(const short8v*)(pb + kt);
        short8v b1 = *(const short8v*)(pb + 64 * HID + kt);
        __syncthreads();
        *(short8v*)la = a0;
        *(short8v*)(la + 64 * 32) = a1;
        *(short8v*)lb = b0;
        *(short8v*)(lb + 64 * 32) = b1;
        __syncthreads();
        short8v av[4], bv[4];
#pragma unroll
        for (int i = 0; i < 4; ++i) av[i] = *(const short8v*)&As[(RM + i * 16 + m) * 32 + q * 8];
#pragma unroll
        for (int j = 0; j < 4; ++j) bv[j] = *(const short8v*)&Bs[(CN + j * 16 + m) * 32 + q * 8];
#pragma unroll
        for (int i = 0; i < 4; ++i)
#pragma unroll
            for (int j = 0; j < 4; ++j)
                acc[i][j] = __builtin_amdgcn_mfma_f32_16x16x32_bf16(av[i], bv[j], acc[i][j], 0, 0, 0);
    }
#pragma unroll
    for (int i = 0; i < 4; ++i)
#pragma unroll
        for (int j = 0; j < 4; ++j)
#pragma unroll
            for (int r = 0; r < 4; ++r) {
                int grow = mtile * 128 + RM + i * 16 + q * 4 + r;
                int gcol = ntile * 128 + CN + j * 16 + m;
                gI[(long)grow * G4 + gcol] = f2bf(acc[i][j][r]);
            }
}

// ---------------- persistent recurrent kernel ----------------
// 64 blocks x 1024 threads. Block bid owns hidden units [bid*16, +16)
// = reordered gate rows [bid*64, +64). 16 waves = 4 unit-groups (ug) x
// 4 batch-groups (bg).
//
// Operand-swapped MFMA: D = W_tile (16 reordered rows = 4 units) x h^T
// (K x 16 batches). C/D layout (col=lane&15, row=q*4+r) puts batch m,
// unit ug*4+q, gates r=0..3 in ONE lane's acc[0..3] -> activation runs
// fully in-register, no LDS gate transpose, no extra barrier.
// h staged once per block into LDS with coalesced agent-scope loads
// (round-0-proven); pitch 1032 shorts => dword pitch 516 (odd*4), so each
// consecutive-8-lane group of the b128 B-reads spreads all 32 banks.
__global__ __launch_bounds__(1024) void lstm_kernel(
    const unsigned short* __restrict__ gI,
    const unsigned short* __restrict__ whh_r,
    const float* __restrict__ bias_r,
    unsigned short* __restrict__ hb0, unsigned short* __restrict__ hb1,
    const float* __restrict__ h0, const float* __restrict__ c0,
    const int* __restrict__ bs_n, const int* __restrict__ offs,
    unsigned* __restrict__ bar,
    float* __restrict__ out, float* __restrict__ hf, float* __restrict__ cf,
    int T)
{
    __shared__ unsigned short hlds[64 * 1032];   // staged h, 132KB
    __shared__ int sbs[1024], soff[1024];

    int tid = threadIdx.x, bid = blockIdx.x;
    int lane = tid & 63;
    int w = tid >> 6;            // wave 0..15
    int m = lane & 15, q = lane >> 4;
    int ug = w & 3, bg = w >> 2; // unit-group, batch-group

    for (int i = tid; i < T && i < 1024; i += 1024) { sbs[i] = bs_n[i]; soff[i] = offs[i]; }

    int brow = bg * 16 + m;            // batch row this lane owns
    int gcol = bid * 16 + ug * 4 + q;  // hidden unit this lane owns
    float c_reg = c0[brow * HID + gcol];
    float h_reg = h0[brow * HID + gcol];
    float4 bia = *(const float4*)&bias_r[gcol * 4];

    // A-fragment (W) base: reordered rows [bid*64 + ug*16, +16), from global
    const unsigned short* wp = whh_r + (size_t)(bid * 64 + ug * 16 + m) * HID + q * 8;
    // B-fragment (h^T) base: staged h rows [bg*16, +16)
    const unsigned short* hp = hlds + (bg * 16 + m) * 1032 + q * 8;

    __syncthreads();

    // gI prefetch pipeline: gv = step t, gvn = step t+1
    ushort4 gv = make_ushort4(0, 0, 0, 0);
    {
        int bs0 = sbs[0];
        if (brow < bs0)
            gv = *(const ushort4*)(gI + (size_t)(soff[0] + brow) * G4 + gcol * 4);
    }

    for (int t = 0; t < T; ++t) {
        const ull* hq = (const ull*)((t & 1) ? hb1 : hb0);
        ull* hn = (ull*)((t & 1) ? hb0 : hb1);
        int bs = sbs[t], off = soff[t];
        int bsn = (t + 1 < T) ? sbs[t + 1] : 0;
        int offn = (t + 1 < T) ? soff[t + 1] : 0;

        // stage h (128KB) into LDS: coalesced agent-scope 8B pairs, all in flight
        ull st[16];
#pragma unroll
        for (int it = 0; it < 8; ++it) {
            int idx = it * 1024 + tid;           // 16B-chunk index
            st[2 * it]     = __hip_atomic_load(hq + 2 * (size_t)idx,
                                               __ATOMIC_RELAXED, __HIP_MEMORY_SCOPE_AGENT);
            st[2 * it + 1] = __hip_atomic_load(hq + 2 * (size_t)idx + 1,
                                               __ATOMIC_RELAXED, __HIP_MEMORY_SCOPE_AGENT);
        }
#pragma unroll
        for (int it = 0; it < 8; ++it) {
            int idx = it * 1024 + tid;
            int row = idx >> 7, slot = idx & 127;
            union { ull u2[2]; short8v s8; } v;
            v.u2[0] = st[2 * it]; v.u2[1] = st[2 * it + 1];
            *(short8v*)(hlds + row * 1032 + slot * 8) = v.s8;
        }
        __syncthreads();   // [A] hlds ready (also drains gv-prefetch dependency)

        // prefetch next step's input-gate slice (hides under MFMA phase)
        ushort4 gvn = make_ushort4(0, 0, 0, 0);
        if (brow < bsn)
            gvn = *(const ushort4*)(gI + (size_t)(offn + brow) * G4 + gcol * 4);

        // gates(h-part): D = W_tile x h^T, one acc chain per lane
        float4v acc = (float4v){0.f, 0.f, 0.f, 0.f};
#pragma unroll
        for (int k = 0; k < 32; ++k) {
            short8v wv = *(const short8v*)(wp + k * 32);
            short8v hv = *(const short8v*)(hp + k * 32);
            acc = __builtin_amdgcn_mfma_f32_16x16x32_bf16(wv, hv, acc, 0, 0, 0);
        }

        // activation fully in-register: lane = (batch brow, unit gcol)
        if (brow < bs) {
            float gi = acc[0] + bia.x + bf2f(gv.x);
            float gf = acc[1] + bia.y + bf2f(gv.y);
            float gg = acc[2] + bia.z + bf2f(gv.z);
            float go = acc[3] + bia.w + bf2f(gv.w);
            float fi = sigm(gi), ff = sigm(gf), fg = tanh_fast(gg), fo = sigm(go);
            c_reg = ff * c_reg + fi * fg;
            float hv2 = fo * tanh_fast(c_reg);
            h_reg = hv2;
            out[(size_t)(off + brow) * HID + gcol] = hv2;
            if (t + 1 >= T || brow >= bsn) {
                hf[brow * HID + gcol] = hv2;
                cf[brow * HID + gcol] = c_reg;
            }
        }
        gv = gvn;

        // publish h: gather 4 units (lanes m, m+16, m+32, m+48) into one 8B
        // agent-scope store by the q==0 lane
        {
            unsigned us = (unsigned)f2bf(h_reg);
            unsigned p1 = (unsigned)__shfl_xor((int)us, 16);
            unsigned w1 = us | (p1 << 16);                 // q0:(u0|u1), q2:(u2|u3)
            unsigned w2 = (unsigned)__shfl_xor((int)w1, 32); // q0 gets q2's pair
            if (q == 0) {
                ull pk = (ull)w1 | ((ull)w2 << 32);
                __hip_atomic_store(hn + (size_t)brow * 256 + bid * 4 + ug, pk,
                                   __ATOMIC_RELAXED, __HIP_MEMORY_SCOPE_AGENT);
            }
        }

        if (t + 1 < T) {
            asm volatile("s_waitcnt vmcnt(0)" ::: "memory");   // publishes drained to IC
            __syncthreads();   // [C] whole block's h published; hlds reads done
            if (tid == 0) {
                __hip_atomic_fetch_add(bar, 1u, __ATOMIC_RELAXED, __HIP_MEMORY_SCOPE_AGENT);
                unsigned tgt = (unsigned)(t + 1) * 64u;
                while (__hip_atomic_load(bar, __ATOMIC_RELAXED, __HIP_MEMORY_SCOPE_AGENT) < tgt)
                    __builtin_amdgcn_s_sleep(1);
            }
            __syncthreads();   // [D] released (single poller + block fan-out)
        }
    }
}

extern "C" void kernel_launch(void* const* d_in, const int* in_sizes, int n_in,
                              void* d_out, int out_size, void* d_ws, size_t ws_size,
                              hipStream_t stream)
{
    const float* data = (const float*)d_in[0];
    const int* bs_raw = (const int*)d_in[1];
    const float* Wih = (const float*)d_in[2];
    const float* Whh = (const float*)d_in[3];
    const float* bih = (const float*)d_in[4];
    const float* bhh = (const float*)d_in[5];
    const float* h0 = (const float*)d_in[6];
    const float* c0 = (const float*)d_in[7];
    int total = in_sizes[0] / HID;     // 47872
    int T = in_sizes[1];               // 1000

    char* p = (char*)d_ws;
    unsigned short* gI = (unsigned short*)p;     p += (size_t)total * G4 * 2;
    unsigned short* xb = (unsigned short*)p;     p += (size_t)total * HID * 2;
    unsigned short* wih_r = (unsigned short*)p;  p += (size_t)G4 * HID * 2;
    unsigned short* whh_r = (unsigned short*)p;  p += (size_t)G4 * HID * 2;
    float* bias_r = (float*)p;                   p += (size_t)G4 * 4;
    unsigned short* hbuf0 = (unsigned short*)p;  p += (size_t)BB * HID * 2;
    unsigned short* hbuf1 = (unsigned short*)p;  p += (size_t)BB * HID * 2;
    int* bs_n = (int*)p;                         p += 4096;
    int* offs = (int*)p;                         p += 4096;
    unsigned* bar = (unsigned*)p;                p += 256;

    float* out = (float*)d_out;
    float* hf = out + (size_t)total * HID;
    float* cf = hf + (size_t)BB * HID;

    prep_kernel<<<4097, 256, 0, stream>>>(data, bs_raw, Wih, Whh, bih, bhh, h0,
                                          xb, wih_r, whh_r, bias_r, hbuf0, hbuf1,
                                          bs_n, offs, bar, total, T);
    gemm_kernel<<<dim3(total / 128, G4 / 128), 256, 0, stream>>>(xb, wih_r, gI);
    lstm_kernel<<<64, 1024, 0, stream>>>(gI, whh_r, bias_r, hbuf0, hbuf1, h0, c0,
                                         bs_n, offs, bar, out, hf, cf, T);
}